// Round 11
// baseline (203.431 us; speedup 1.0000x reference)
//
#include <hip/hip_runtime.h>
#include <math.h>

#define NG 5
#define NF 5
#define NR 5
#define NW 4
#define STEP 16          // 1 + NG + NF + NR
#define M_OTH 15         // NG + NF + NR
#define NB 60            // NW * M_OTH
#define L 512            // MAXLEN
#define FEAT 64
#define GAMMA 5.0f
#define SEGN 11          // STEP - NR
#define NSEG 44          // NW * SEGN
#define SEGD 32768       // MAXLEN * FEAT

#define C1   0.28853900817779268f   // 1/(GAMMA*ln2)
#define GLN2 3.4657359027997265f    // GAMMA*ln2
#define BIGS 2.8853900e9f           // 1e10*C1 (acts as +inf in scaled domain)
#define BNDK 136                    // boundary k-slots per tier (kcap<=127, +pad)
#define GRAM_BLK0 60
#define DSTRIDE 262144              // 128 slots * 256 G * 8 floats per problem

// ---------------------------------------------------------------------------
// K1: pairwise sqdist -> C1-scaled, stored in the C=4/R=2 DTW layout:
//   data cell (ii, jj) [0-based]:  G = ii>>1, k = jj>>2,
//   DS[b][ (k+G)&127 ][ G ][ ((jj&3)<<1)|(ii&1) ]
// At global DTW step tt all lanes read slot (tt&127): 32 contiguous B/lane.
// Tiles with ti>=la or tj>=lb skipped (never reach the capture cell).
// ---------------------------------------------------------------------------
__global__ __launch_bounds__(256, 2) void sqdist_kernel(const float* __restrict__ data,
                                                        const int* __restrict__ lens,
                                                        float* __restrict__ DS) {
    int b = blockIdx.z;
    int w = b / M_OTH, m = b % M_OTH;
    int la = lens[w * STEP];
    int lb = lens[w * STEP + 1 + m];
    int ti = blockIdx.y * 128;
    int tj = blockIdx.x * 128;
    if (ti >= la || tj >= lb) return;            // never consumed

    const float* X = data + (size_t)(w * STEP) * L * FEAT;            // anchor (i)
    const float* Y = data + (size_t)(w * STEP + 1 + m) * L * FEAT;    // other (j)

    __shared__ float Xs[128][68];
    __shared__ float Ys[128][68];
    __shared__ float nx[128], ny[128];

    int t = threadIdx.y * 16 + threadIdx.x;
    #pragma unroll
    for (int k = 0; k < 8; ++k) {
        int idx = t + k * 256;
        int r = idx >> 4, c = (idx & 15) * 4;
        *(float4*)&Xs[r][c] = *(const float4*)(X + (size_t)(ti + r) * FEAT + c);
        *(float4*)&Ys[r][c] = *(const float4*)(Y + (size_t)(tj + r) * FEAT + c);
    }
    __syncthreads();
    {   // row norms
        int r = t & 127;
        const float* row = (t < 128) ? Xs[r] : Ys[r];
        float s = 0.f;
        #pragma unroll
        for (int f = 0; f < 64; f += 4) {
            float4 v = *(const float4*)&row[f];
            s += v.x * v.x + v.y * v.y + v.z * v.z + v.w * v.w;
        }
        if (t < 128) nx[r] = s; else ny[r] = s;
    }
    __syncthreads();

    int tx = threadIdx.x, ty = threadIdx.y;   // ii = 16a+tx, jj = 16c+ty
    float acc[8][8] = {};
    for (int f = 0; f < 64; f += 4) {
        float4 xv[8], yv[8];
        #pragma unroll
        for (int a = 0; a < 8; ++a) xv[a] = *(const float4*)&Xs[16 * a + tx][f];
        #pragma unroll
        for (int c = 0; c < 8; ++c) yv[c] = *(const float4*)&Ys[16 * c + ty][f];
        #pragma unroll
        for (int a = 0; a < 8; ++a)
            #pragma unroll
            for (int c = 0; c < 8; ++c)
                acc[a][c] += xv[a].x * yv[c].x + xv[a].y * yv[c].y +
                             xv[a].z * yv[c].z + xv[a].w * yv[c].w;
    }
    size_t base = (size_t)b * DSTRIDE;
    #pragma unroll
    for (int a = 0; a < 8; ++a) {
        int ii = ti + 16 * a + tx;
        float xn = nx[16 * a + tx];
        int G = ii >> 1;
        #pragma unroll
        for (int c = 0; c < 8; ++c) {
            int jj = tj + 16 * c + ty;
            float d = xn + ny[16 * c + ty] - 2.0f * acc[a][c];
            int slot = ((jj >> 2) + G) & 127;
            int inner = ((jj & 3) << 1) | (ii & 1);
            DS[base + (size_t)slot * 2048 + G * 8 + inner] = fmaxf(d, 0.0f) * C1;
        }
    }
}

// up[l] = x[l-1] via DPP: row_shr:1; row_bcast15 patches lanes 16/32/48.
__device__ __forceinline__ float dpp_up(float x, bool rh) {
    int xi = __float_as_int(x);
    int sh  = __builtin_amdgcn_update_dpp(xi, xi, 0x111, 0xF, 0xF, false); // row_shr:1
    int b15 = __builtin_amdgcn_update_dpp(xi, xi, 0x142, 0xF, 0xF, false); // row_bcast15
    return __int_as_float(rh ? b15 : sh);
}

// deferred-log softmin cell with min3 reference (exact, overflow-safe):
#define CELL(qp, qs, pa, sa, pb, sb, pc, sc, Dv)                          \
    {                                                                     \
        float ref = fminf(fminf((pa), (pb)), (pc));                       \
        float eA = __builtin_amdgcn_exp2f(ref - (pa));                    \
        float eB = __builtin_amdgcn_exp2f(ref - (pb));                    \
        float eC = __builtin_amdgcn_exp2f(ref - (pc));                    \
        qs = fmaf(eA, (sa), fmaf(eB, (sb), eC * (sc)));                   \
        qp = (Dv) + ref;                                                  \
    }

// ---------------------------------------------------------------------------
// gram tile body (blocks 60..125): 4x4 segment tile, 256 threads.
// ---------------------------------------------------------------------------
__device__ void gram_body(const float* __restrict__ data, float* __restrict__ Gm, int f) {
    int bx = 0, rem = f;
    for (int q = 0; q < 11; ++q) { int c = 11 - q; if (rem < c) { bx = q; break; } rem -= c; }
    int by = bx + rem;
    int t = threadIdx.x;
    int lane = t & 63, wv = t >> 6;
    const float* pa[4];
    const float* pb[4];
    #pragma unroll
    for (int i = 0; i < 4; ++i) {
        int sa = bx * 4 + i;
        int sb = by * 4 + i;
        pa[i] = data + (size_t)((sa / SEGN) * STEP + (sa % SEGN)) * SEGD;
        pb[i] = data + (size_t)((sb / SEGN) * STEP + (sb % SEGN)) * SEGD;
    }
    float acc[16] = {};
    for (int d = t * 4; d < SEGD; d += 1024) {
        float4 ra[4], rb[4];
        #pragma unroll
        for (int i = 0; i < 4; ++i) ra[i] = *(const float4*)(pa[i] + d);
        #pragma unroll
        for (int i = 0; i < 4; ++i) rb[i] = *(const float4*)(pb[i] + d);
        #pragma unroll
        for (int i = 0; i < 4; ++i)
            #pragma unroll
            for (int jj = 0; jj < 4; ++jj)
                acc[i * 4 + jj] += ra[i].x * rb[jj].x + ra[i].y * rb[jj].y +
                                   ra[i].z * rb[jj].z + ra[i].w * rb[jj].w;
    }
    #pragma unroll
    for (int i = 0; i < 16; ++i)
        #pragma unroll
        for (int s = 32; s > 0; s >>= 1)
            acc[i] += __shfl_xor(acc[i], s);
    __shared__ float part[4][16];
    if (lane == 0)
        #pragma unroll
        for (int i = 0; i < 16; ++i) part[wv][i] = acc[i];
    __syncthreads();
    if (t < 16) {
        float s = part[0][t] + part[1][t] + part[2][t] + part[3][t];
        int a = bx * 4 + (t >> 2), c = by * 4 + (t & 3);
        Gm[a * NSEG + c] = s;
        Gm[c * NSEG + a] = s;
    }
}

// ---------------------------------------------------------------------------
// K2: soft-DTW (blocks 0..59) + gram (blocks 60..125).
// DTW: 4 waves, lane G owns DP rows {2G+1, 2G+2}; at global step tt processes
// the 4-column pair-block k = tt-G (DP cols 4k+1..4k+4): 8 cells per step.
// Deferred-log (V = P - log2 s) with min3 reference; renorm every 4 steps.
// Cross-lane via DPP; cross-wave via k-indexed write-once LDS slots.
// RACE-SAFE chunk consume: every consumed word is validated via a
// NaN-propagating checksum (sentinel can't hide); dirty -> poll + acquire
// fence + re-read + re-validate loop. Slots beyond kcap stay NaN but only
// feed columns > lb, which provably never reach the captured cell.
// ---------------------------------------------------------------------------
__global__ __launch_bounds__(256) void dtw_gram_kernel(const float* __restrict__ DS,
                                                       const int* __restrict__ lens,
                                                       const float* __restrict__ data,
                                                       float* __restrict__ res,
                                                       float* __restrict__ Gm) {
    int blk = blockIdx.x;
    if (blk >= GRAM_BLK0) { gram_body(data, Gm, blk - GRAM_BLK0); return; }

    int b = blk;
    int w_ = b / M_OTH, m = b % M_OTH;
    int la = lens[w_ * STEP];
    int lb = lens[w_ * STEP + 1 + m];
    int tid = threadIdx.x;
    int W = tid >> 6, l = tid & 63, G = tid;
    bool rh = ((l & 15) == 0);
    const float* dsb = DS + (size_t)b * DSTRIDE;

    __shared__ float bndF[3][BNDK * 8];
    for (int k = tid; k < 3 * BNDK * 8; k += 256)
        ((float*)bndF)[k] = __int_as_float(0x7FC00000);   // NaN sentinel
    __syncthreads();                     // only barrier on the DTW path

    int gstar = (la - 1) >> 1;           // lane holding row la
    int rstar = (la - 1) & 1;
    int kcap  = (lb - 1) >> 2;           // pair-block holding col lb
    int cstar = (lb - 1) & 3;
    int tcap  = kcap + gstar;
    if (64 * W > gstar) return;
    int gmax = min(64 * W + 63, gstar);
    int t0 = 64 * W;
    int tend = kcap + gmax;
    bool pubw = (W < 3);

    // state: (p,s) pairs, V = P - log2 s
    float p0 = BIGS, s0 = 1.f;           // R(2G+1, last col of prev block)
    float p1 = BIGS, s1 = 1.f;           // R(2G+2, ...)
    float pC = (G == 0) ? 0.f : BIGS;    // R(2G, ...); R(0,0)=0
    float sC = 1.f;
    float outp = BIGS, outs = 1.f;

    float4 ringA[4], ringB[4];           // D prefetch (static idx via unroll)
    #pragma unroll
    for (int kk = 0; kk < 4; ++kk) {
        const float* pp = dsb + (size_t)((t0 + kk) & 127) * 2048 + G * 8;
        ringA[kk] = *(const float4*)pp;
        ringB[kk] = *(const float4*)(pp + 4);
    }
    float4 chA[4], chB[4];               // boundary chunk (4 k-slots)
    if (W == 0) {
        #pragma unroll
        for (int kk = 0; kk < 4; ++kk) {
            chA[kk] = make_float4(BIGS, 1.f, BIGS, 1.f);
            chB[kk] = make_float4(BIGS, 1.f, BIGS, 1.f);
        }
    } else {
        const float* src = &bndF[W - 1][0];
        #pragma unroll
        for (int kk = 0; kk < 4; ++kk) {
            chA[kk] = *(const float4*)(src + kk * 8);
            chB[kk] = *(const float4*)(src + kk * 8 + 4);
        }
    }
    // DPP-carried incoming A pairs (row 2G at the 4 cols of my current block)
    float nxP0 = BIGS, nxS0 = 1.f, nxP1 = BIGS, nxS1 = 1.f;
    float nxP2 = BIGS, nxS2 = 1.f, nxP3 = BIGS, nxS3 = 1.f;
    bool isl0 = (l == 0);

    for (int tbase = t0; tbase <= tend; tbase += 4) {
        int kb = tbase - 64 * W;         // lane0's k for sub-step 0 (uniform)
        if (W > 0 && kb <= kcap) {
            // ---- race-safe validation of ALL consumed words ----
            int vidx = min(kb + 3, kcap);
            const float* vp  = &bndF[W - 1][vidx * 8 + 6];   // q7p guard word
            const float* src = &bndF[W - 1][(size_t)kb * 8];
            for (;;) {
                float chk = 0.f;         // NaN-propagating checksum (finite data)
                #pragma unroll
                for (int kk = 0; kk < 4; ++kk) {
                    if (kb + kk <= kcap)
                        chk += chA[kk].x + chA[kk].y + chA[kk].z + chA[kk].w +
                               chB[kk].x + chB[kk].y + chB[kk].z + chB[kk].w;
                }
                if (!__builtin_isnan(chk)) break;
                float v = __hip_atomic_load(vp, __ATOMIC_RELAXED,
                                            __HIP_MEMORY_SCOPE_WORKGROUP);
                while (__builtin_isnan(v)) {
                    __builtin_amdgcn_s_sleep(1);
                    v = __hip_atomic_load(vp, __ATOMIC_RELAXED,
                                          __HIP_MEMORY_SCOPE_WORKGROUP);
                }
                __builtin_amdgcn_fence(__ATOMIC_ACQUIRE, "workgroup");
                #pragma unroll
                for (int kk = 0; kk < 4; ++kk) {
                    chA[kk] = *(const float4*)(src + kk * 8);
                    chB[kk] = *(const float4*)(src + kk * 8 + 4);
                }
            }
        }
        #pragma unroll
        for (int kk = 0; kk < 4; ++kk) {
            int tt = tbase + kk;
            bool act = (tt >= G);
            float4 Da = ringA[kk], Dbv = ringB[kk];
            {   // prefetch step tt+4
                const float* pp = dsb + (size_t)((tt + 4) & 127) * 2048 + G * 8;
                ringA[kk] = *(const float4*)pp;
                ringB[kk] = *(const float4*)(pp + 4);
            }
            // incoming A pairs: lane0 from chunk (or BIGS for W=0), else DPP
            float iP0 = isl0 ? chA[kk].x : nxP0, iS0 = isl0 ? chA[kk].y : nxS0;
            float iP1 = isl0 ? chA[kk].z : nxP1, iS1 = isl0 ? chA[kk].w : nxS1;
            float iP2 = isl0 ? chB[kk].x : nxP2, iS2 = isl0 ? chB[kk].y : nxS2;
            float iP3 = isl0 ? chB[kk].z : nxP3, iS3 = isl0 ? chB[kk].w : nxS3;
            // 8 cells (col-major, rows r0=2G+1, r1=2G+2)
            float q0p, q0s, q1p, q1s, q2p, q2s, q3p, q3s;
            float q4p, q4s, q5p, q5s, q6p, q6s, q7p, q7s;
            CELL(q0p, q0s, iP0, iS0, p0, s0, pC, sC, Da.x);
            CELL(q1p, q1s, q0p, q0s, p1, s1, p0, s0, Da.y);
            CELL(q2p, q2s, iP1, iS1, q0p, q0s, iP0, iS0, Da.z);
            CELL(q3p, q3s, q2p, q2s, q1p, q1s, q0p, q0s, Da.w);
            CELL(q4p, q4s, iP2, iS2, q2p, q2s, iP1, iS1, Dbv.x);
            CELL(q5p, q5s, q4p, q4s, q3p, q3s, q2p, q2s, Dbv.y);
            CELL(q6p, q6s, iP3, iS3, q4p, q4s, iP2, iS2, Dbv.z);
            CELL(q7p, q7s, q6p, q6s, q5p, q5s, q4p, q4s, Dbv.w);
            if (tt == tcap) {            // uniform, rare
                if (G == gstar) {
                    int sel = (cstar << 1) | rstar;
                    float cp, cs;
                    if (sel == 0)      { cp = q0p; cs = q0s; }
                    else if (sel == 1) { cp = q1p; cs = q1s; }
                    else if (sel == 2) { cp = q2p; cs = q2s; }
                    else if (sel == 3) { cp = q3p; cs = q3s; }
                    else if (sel == 4) { cp = q4p; cs = q4s; }
                    else if (sel == 5) { cp = q5p; cs = q5s; }
                    else if (sel == 6) { cp = q6p; cs = q6s; }
                    else               { cp = q7p; cs = q7s; }
                    outp = cp; outs = cs;
                }
            }
            // state update (frozen pre-activation to preserve the BIG wall)
            p0 = act ? q6p : p0;  s0 = act ? q6s : s0;
            p1 = act ? q7p : p1;  s1 = act ? q7s : s1;
            pC = act ? iP3 : pC;  sC = act ? iS3 : sC;
            // publish bottom row (r1) at the 4 cols
            if (pubw && l == 63 && act) {
                int k63 = tt - G;
                float* dst = &bndF[W][(size_t)k63 * 8];
                *(float4*)dst       = make_float4(q1p, q1s, q3p, q3s);
                *(float4*)(dst + 4) = make_float4(q5p, q5s, q7p, q7s);
            }
            // DPP for next step's incoming A
            nxP0 = dpp_up(q1p, rh); nxS0 = dpp_up(q1s, rh);
            nxP1 = dpp_up(q3p, rh); nxS1 = dpp_up(q3s, rh);
            nxP2 = dpp_up(q5p, rh); nxS2 = dpp_up(q5s, rh);
            nxP3 = dpp_up(q7p, rh); nxS3 = dpp_up(q7s, rh);
        }
        // renormalize state every 4 steps (s bounded ~3^40, exact V preserved)
        p0 -= __builtin_amdgcn_logf(s0); s0 = 1.f;
        p1 -= __builtin_amdgcn_logf(s1); s1 = 1.f;
        // speculative read of next chunk (validated next iteration)
        if (W > 0) {
            int sb_ = min(kb + 4, BNDK - 4);
            const float* src = &bndF[W - 1][(size_t)sb_ * 8];
            #pragma unroll
            for (int kk = 0; kk < 4; ++kk) {
                chA[kk] = *(const float4*)(src + kk * 8);
                chB[kk] = *(const float4*)(src + kk * 8 + 4);
            }
        }
    }
    if (G == gstar)
        res[b] = (outp - __builtin_amdgcn_logf(outs)) * GLN2 / (float)(la + lb);
}

// ---------------------------------------------------------------------------
// K3: finalize — losses + 9 MMDs, wave-shuffle reductions.
// ---------------------------------------------------------------------------
__global__ __launch_bounds__(512) void finalize_kernel(const float* __restrict__ res,
                                                       const float* __restrict__ G,
                                                       float* __restrict__ out) {
    __shared__ float wpart[9][8];
    __shared__ float bws[9];
    __shared__ float mmds[9];
    __shared__ float wloss[NW];
    __shared__ int   wnzr[NW];
    int t = threadIdx.x, lane = t & 63, wv = t >> 6;

    if (t < NW) {
        int w = t;
        float dg[NG], dn[NF + NR];
        for (int g = 0; g < NG; ++g) dg[g] = res[w * M_OTH + g];
        for (int q2 = 0; q2 < NF + NR; ++q2) dn[q2] = res[w * M_OTH + NG + q2];
        float sum_s = 0.f, sum_r = 0.f;
        int nzs = 0, nzr = 0;
        for (int g = 0; g < NG; ++g) {
            for (int f = 0; f < NF; ++f) {
                float v = dg[g] + 1.0f - dn[f];
                if (v > 0.f) { sum_s += v; nzs++; }
            }
            for (int r = 0; r < NR; ++r) {
                float v = dg[g] + 1.5f - dn[NF + r];
                if (v > 0.f) { sum_r += v; nzr++; }
            }
        }
        float ca = (dg[0] + dg[1] + dg[2] + dg[3] + dg[4]) / 5.0f;
        float cb = (dn[0] + dn[1] + dn[2] + dn[3]) * 0.25f;
        float intra = 0.f;
        for (int g = 0; g < NG; ++g) intra += dg[g] - ca;
        float inter = fmaxf(0.f, 1.0f - fabsf(ca - cb));
        float lv = (sum_s + sum_r) / (float)(nzs + nzr + 1);
        float bce = 0.f;
        for (int r = 0; r < NR; ++r) {
            float x = dn[NF + r] - dg[0];
            float ls = (x >= 0.f) ? -log1pf(expf(-x)) : (x - log1pf(expf(x)));
            bce += ls;
        }
        bce = -bce / 5.0f;
        wloss[w] = bce + lv + intra * 0.01f + inter * 0.01f;
        wnzr[w] = nzr;
    }

    const int pi[9] = {0, 0, 0, 1, 1, 2, 2, 3, 3};
    const int pj[9] = {1, 2, 3, 2, 3, 1, 3, 1, 2};
    int pp = t / 22, qq = t % 22;
    bool act = t < 484;
    float l2v[9];
    #pragma unroll
    for (int p = 0; p < 9; ++p) {
        float v = 0.f;
        if (act) {
            int wi = pi[p], wj = pj[p];
            int gp = (pp < 11) ? wi * SEGN + pp : wj * SEGN + (pp - 11);
            int gq = (qq < 11) ? wi * SEGN + qq : wj * SEGN + (qq - 11);
            v = fmaxf(G[gp * NSEG + gp] + G[gq * NSEG + gq] - 2.f * G[gp * NSEG + gq], 0.f);
        }
        l2v[p] = v;
    }
    #pragma unroll
    for (int p = 0; p < 9; ++p) {
        float r = l2v[p];
        #pragma unroll
        for (int s = 32; s > 0; s >>= 1) r += __shfl_xor(r, s);
        if (lane == 0) wpart[p][wv] = r;
    }
    __syncthreads();
    if (t < 9) {
        float s = 0.f;
        #pragma unroll
        for (int k = 0; k < 8; ++k) s += wpart[t][k];
        bws[t] = s * (1.0f / 462.0f) * 0.25f;
    }
    __syncthreads();
    float sgn = ((pp < 11) == (qq < 11)) ? 1.f : -1.f;
    #pragma unroll
    for (int p = 0; p < 9; ++p) {
        float kv = 0.f;
        if (act) {
            float x = -l2v[p] / bws[p];
            kv = sgn * (__expf(x) + __expf(x * 0.5f) + __expf(x * 0.25f) +
                        __expf(x * 0.125f) + __expf(x * 0.0625f));
        }
        #pragma unroll
        for (int s = 32; s > 0; s >>= 1) kv += __shfl_xor(kv, s);
        if (lane == 0) wpart[p][wv] = kv;
    }
    __syncthreads();
    if (t < 9) {
        float s = 0.f;
        #pragma unroll
        for (int k = 0; k < 8; ++k) s += wpart[t][k];
        mmds[t] = s / 121.0f;
    }
    __syncthreads();
    if (t == 0) {
        float loss = 0.25f * (wloss[0] + wloss[1] + wloss[2] + wloss[3]);
        float mx = 0.f;
        for (int p = 0; p < 9; ++p) mx = fmaxf(mx, mmds[p]);
        out[0] = loss + 0.1f * mx;
        out[1] = (float)(wnzr[0] + wnzr[1] + wnzr[2] + wnzr[3]);
    }
}

// ---------------------------------------------------------------------------
extern "C" void kernel_launch(void* const* d_in, const int* in_sizes, int n_in,
                              void* d_out, int out_size, void* d_ws, size_t ws_size,
                              hipStream_t stream) {
    const float* data = (const float*)d_in[0];
    const int* lens = (const int*)d_in[1];

    float* DS  = (float*)d_ws;                               // 60 * 262144 floats
    float* res = DS + (size_t)NB * DSTRIDE;                  // 60 floats
    float* G   = res + 64;                                   // 44*44 floats
    float* out = (float*)d_out;

    dim3 g1(4, 4, NB), b1(16, 16);
    sqdist_kernel<<<g1, b1, 0, stream>>>(data, lens, DS);
    dtw_gram_kernel<<<GRAM_BLK0 + 66, 256, 0, stream>>>(DS, lens, data, res, G);
    finalize_kernel<<<1, 512, 0, stream>>>(res, G, out);
}

// Round 12
// 168.191 us; speedup vs baseline: 1.2095x; 1.2095x over previous
//
#include <hip/hip_runtime.h>
#include <math.h>

#define NG 5
#define NF 5
#define NR 5
#define NW 4
#define STEP 16          // 1 + NG + NF + NR
#define M_OTH 15         // NG + NF + NR
#define NB 60            // NW * M_OTH
#define L 512            // MAXLEN
#define FEAT 64
#define GAMMA 5.0f
#define SEGN 11          // STEP - NR
#define NSEG 44          // NW * SEGN
#define SEGD 32768       // MAXLEN * FEAT

#define C1   0.28853900817779268f   // 1/(GAMMA*ln2)
#define GLN2 3.4657359027997265f    // GAMMA*ln2
#define BIGS 2.8853900e9f           // 1e10*C1 (acts as +inf in scaled domain)
#define BNDW 800                    // boundary slots (max touched idx ~797)
#define GRAM_BLK0 60

// ---------------------------------------------------------------------------
// K1: pairwise sqdist, 128x128 tiles, norm-form, skewed mod-512 layout,
// pre-scaled by C1:  DS[b][(jj + (ii>>1)) & 511][ii] = C1*dist(a_ii, o_jj).
// Tiles with ti>=la or tj>=lb are skipped: their values provably never reach
// the captured DTW cell (deps flow only toward larger i,j; garbage is finite).
// ---------------------------------------------------------------------------
__global__ __launch_bounds__(256, 2) void sqdist_kernel(const float* __restrict__ data,
                                                        const int* __restrict__ lens,
                                                        float* __restrict__ DS) {
    int b = blockIdx.z;
    int w = b / M_OTH, m = b % M_OTH;
    int la = lens[w * STEP];
    int lb = lens[w * STEP + 1 + m];
    int ti = blockIdx.y * 128;
    int tj = blockIdx.x * 128;
    if (ti >= la || tj >= lb) return;            // never consumed

    const float* X = data + (size_t)(w * STEP) * L * FEAT;            // anchor (i)
    const float* Y = data + (size_t)(w * STEP + 1 + m) * L * FEAT;    // other (j)

    __shared__ float Xs[128][68];
    __shared__ float Ys[128][68];
    __shared__ float nx[128], ny[128];

    int t = threadIdx.y * 16 + threadIdx.x;
    #pragma unroll
    for (int k = 0; k < 8; ++k) {
        int idx = t + k * 256;
        int r = idx >> 4, c = (idx & 15) * 4;
        *(float4*)&Xs[r][c] = *(const float4*)(X + (size_t)(ti + r) * FEAT + c);
        *(float4*)&Ys[r][c] = *(const float4*)(Y + (size_t)(tj + r) * FEAT + c);
    }
    __syncthreads();
    {   // row norms
        int r = t & 127;
        const float* row = (t < 128) ? Xs[r] : Ys[r];
        float s = 0.f;
        #pragma unroll
        for (int f = 0; f < 64; f += 4) {
            float4 v = *(const float4*)&row[f];
            s += v.x * v.x + v.y * v.y + v.z * v.z + v.w * v.w;
        }
        if (t < 128) nx[r] = s; else ny[r] = s;
    }
    __syncthreads();

    int tx = threadIdx.x, ty = threadIdx.y;   // ii = 16a+tx, jj = 16c+ty (strided)
    float acc[8][8] = {};
    for (int f = 0; f < 64; f += 4) {
        float4 xv[8], yv[8];
        #pragma unroll
        for (int a = 0; a < 8; ++a) xv[a] = *(const float4*)&Xs[16 * a + tx][f];
        #pragma unroll
        for (int c = 0; c < 8; ++c) yv[c] = *(const float4*)&Ys[16 * c + ty][f];
        #pragma unroll
        for (int a = 0; a < 8; ++a)
            #pragma unroll
            for (int c = 0; c < 8; ++c)
                acc[a][c] += xv[a].x * yv[c].x + xv[a].y * yv[c].y +
                             xv[a].z * yv[c].z + xv[a].w * yv[c].w;
    }
    #pragma unroll
    for (int a = 0; a < 8; ++a) {
        int ii = ti + 16 * a + tx;
        float xn = nx[16 * a + tx];
        #pragma unroll
        for (int c = 0; c < 8; ++c) {
            int jj = tj + 16 * c + ty;
            float d = xn + ny[16 * c + ty] - 2.0f * acc[a][c];
            size_t idx = ((size_t)b * 512 + ((jj + (ii >> 1)) & 511)) * 512 + ii;
            DS[idx] = fmaxf(d, 0.0f) * C1;
        }
    }
}

// up[l] = x[l-1] via DPP (no LDS): row_shr:1 + row_bcast15 fixes lanes 16/32/48.
__device__ __forceinline__ float dpp_shift_up1(float x) {
    int xi = __float_as_int(x);
    int sh  = __builtin_amdgcn_update_dpp(xi, xi, 0x111, 0xF, 0xF, false); // row_shr:1
    int b15 = __builtin_amdgcn_update_dpp(xi, xi, 0x142, 0xF, 0xF, false); // row_bcast15
    int lane = (int)(threadIdx.x & 63);
    int r = ((lane & 15) == 0) ? b15 : sh;
    return __int_as_float(r);
}

// ---------------------------------------------------------------------------
// gram tile body (blocks 60..125): 4x4 segment tile, 256 threads.
// ---------------------------------------------------------------------------
__device__ void gram_body(const float* __restrict__ data, float* __restrict__ Gm, int f) {
    int bx = 0, rem = f;
    for (int q = 0; q < 11; ++q) { int c = 11 - q; if (rem < c) { bx = q; break; } rem -= c; }
    int by = bx + rem;
    int t = threadIdx.x;
    int lane = t & 63, wv = t >> 6;
    const float* pa[4];
    const float* pb[4];
    #pragma unroll
    for (int i = 0; i < 4; ++i) {
        int sa = bx * 4 + i;
        int sb = by * 4 + i;
        pa[i] = data + (size_t)((sa / SEGN) * STEP + (sa % SEGN)) * SEGD;
        pb[i] = data + (size_t)((sb / SEGN) * STEP + (sb % SEGN)) * SEGD;
    }
    float acc[16] = {};
    for (int d = t * 4; d < SEGD; d += 1024) {
        float4 ra[4], rb[4];
        #pragma unroll
        for (int i = 0; i < 4; ++i) ra[i] = *(const float4*)(pa[i] + d);
        #pragma unroll
        for (int i = 0; i < 4; ++i) rb[i] = *(const float4*)(pb[i] + d);
        #pragma unroll
        for (int i = 0; i < 4; ++i)
            #pragma unroll
            for (int jj = 0; jj < 4; ++jj)
                acc[i * 4 + jj] += ra[i].x * rb[jj].x + ra[i].y * rb[jj].y +
                                   ra[i].z * rb[jj].z + ra[i].w * rb[jj].w;
    }
    #pragma unroll
    for (int i = 0; i < 16; ++i)
        #pragma unroll
        for (int s = 32; s > 0; s >>= 1)
            acc[i] += __shfl_xor(acc[i], s);
    __shared__ float part[4][16];
    if (lane == 0)
        #pragma unroll
        for (int i = 0; i < 16; ++i) part[wv][i] = acc[i];
    __syncthreads();
    if (t < 16) {
        float s = part[0][t] + part[1][t] + part[2][t] + part[3][t];
        int a = bx * 4 + (t >> 2), c = by * 4 + (t & 3);
        Gm[a * NSEG + c] = s;
        Gm[c * NSEG + a] = s;
    }
}

// ---------------------------------------------------------------------------
// K2: soft-DTW (blocks 0..59) + gram (blocks 60..125).  [round-6 structure]
// DTW: 4 waves, lane G owns rows 2G+1,2G+2; col j = tt-G+1 at step tt.
// Cross-lane via DPP; cross-wave via write-once NaN-sentinel LDS slots,
// consumed in 16-slot chunks. RACE-SAFE consume: every consumed word is
// validated via a NaN-propagating checksum; dirty -> poll guard + acquire
// fence + re-read + re-validate loop (write-once slots make this exact).
// D reads: 16-deep register prefetch ring (vs 8) to cover L3 latency.
// ---------------------------------------------------------------------------
__global__ __launch_bounds__(256) void dtw_gram_kernel(const float* __restrict__ DS,
                                                       const int* __restrict__ lens,
                                                       const float* __restrict__ data,
                                                       float* __restrict__ res,
                                                       float* __restrict__ Gm) {
    int blk = blockIdx.x;
    if (blk >= GRAM_BLK0) { gram_body(data, Gm, blk - GRAM_BLK0); return; }

    int b = blk;
    int w_ = b / M_OTH, m = b % M_OTH;
    int la = lens[w_ * STEP];
    int lb = lens[w_ * STEP + 1 + m];
    int tid = threadIdx.x;
    int W = tid >> 6, l = tid & 63, G = tid;
    const float* Db = DS + (size_t)b * 512 * 512;

    __shared__ float bnd[3][BNDW];
    for (int k = tid; k < 3 * BNDW; k += 256)
        ((float*)bnd)[k] = __int_as_float(0x7FC00000);   // NaN sentinel
    __syncthreads();                                     // only barrier (DTW path)

    int gstar = (la - 1) >> 1;
    int rstar = (la - 1) & 1;
    int tcap = lb + gstar - 1;
    if (64 * W > gstar) return;
    int gmax = min(64 * W + 63, gstar);
    int t0 = 64 * W;
    int tend = lb + gmax - 1;
    int needmax = lb + 64 * W - 1;     // last step needing a boundary (W>0)
    bool pub = (W < 3);

    float nv0 = BIGS, nv1 = BIGS;      // R(2G+1, j-1), R(2G+2, j-1)  (scaled)
    float A0 = BIGS;                   // R(2G, j)
    float C0 = (G == 0) ? 0.0f : BIGS; // R(2G, j-1); R(0,0)=0
    float out = 0.0f;

    float2 ring[16];                   // D prefetch ring (static idx)
    #pragma unroll
    for (int k = 0; k < 16; ++k)
        ring[k] = *(const float2*)&Db[(size_t)((t0 + k) & 511) * 512 + 2 * G];
    float ch[16];                      // boundary chunk (static idx)
    #pragma unroll
    for (int k = 0; k < 16; ++k) ch[k] = __int_as_float(0x7FC00000);

    int j = 1 - l;                     // column at step t0: t0 - G + 1 = 1 - l
    const float* bsrc = (W > 0) ? bnd[W - 1] : bnd[0];

    for (int t = t0; t <= tend; t += 16) {
        if (W > 0 && t <= needmax) {   // race-safe validation of consumed words
            int lastIdx = min(t + 15, needmax);
            for (;;) {
                float chk = 0.f;       // NaN-propagating checksum (finite data)
                #pragma unroll
                for (int k = 0; k < 16; ++k)
                    if (t + k <= needmax) chk += ch[k];
                if (!__builtin_isnan(chk)) break;
                float v = __hip_atomic_load(&bsrc[lastIdx], __ATOMIC_RELAXED,
                                            __HIP_MEMORY_SCOPE_WORKGROUP);
                while (__builtin_isnan(v)) {
                    __builtin_amdgcn_s_sleep(2);
                    v = __hip_atomic_load(&bsrc[lastIdx], __ATOMIC_RELAXED,
                                          __HIP_MEMORY_SCOPE_WORKGROUP);
                }
                __builtin_amdgcn_fence(__ATOMIC_ACQUIRE, "workgroup");
                #pragma unroll
                for (int k = 0; k < 4; ++k) {
                    float4 c = *(const float4*)&bsrc[t + 4 * k];
                    ch[4 * k] = c.x; ch[4 * k + 1] = c.y;
                    ch[4 * k + 2] = c.z; ch[4 * k + 3] = c.w;
                }
            }
        }
        #pragma unroll
        for (int k = 0; k < 16; ++k) {
            int tt = t + k;
            float l0 = BIGS;
            if (W > 0) l0 = (tt <= needmax) ? ch[k] : BIGS;
            A0 = (l == 0) ? l0 : A0;
            float D0 = ring[k].x, D1 = ring[k].y;
            ring[k] = *(const float2*)&Db[(size_t)((tt + 16) & 511) * 512 + 2 * G];
            // off-chain: E2 = 1 + exp2(min-max) for the (B,C) pairs
            float m2a = fminf(nv0, C0), mxa = fmaxf(nv0, C0);
            float E2a = 1.0f + __builtin_amdgcn_exp2f(m2a - mxa);
            float m2b = fminf(nv1, nv0), mxb = fmaxf(nv1, nv0);
            float E2b = 1.0f + __builtin_amdgcn_exp2f(m2b - mxb);
            // serial chain (2 cells)
            float mn0 = fminf(A0, m2a);
            float s0 = __builtin_amdgcn_exp2f(mn0 - A0) +
                       E2a * __builtin_amdgcn_exp2f(mn0 - m2a);
            float t0v = D0 + (mn0 - __builtin_amdgcn_logf(s0));
            float mn1 = fminf(t0v, m2b);
            float s1 = __builtin_amdgcn_exp2f(mn1 - t0v) +
                       E2b * __builtin_amdgcn_exp2f(mn1 - m2b);
            float t1v = D1 + (mn1 - __builtin_amdgcn_logf(s1));
            bool valid = (unsigned)(j - 1) < (unsigned)L;
            nv0 = valid ? t0v : nv0;
            nv1 = valid ? t1v : nv1;
            if (tt == tcap) { if (G == gstar) out = rstar ? nv1 : nv0; }
            float up = dpp_shift_up1(nv1);               // VALU-only lane shift
            if (pub && l == 63)
                __hip_atomic_store(&bnd[W][tt + 1], nv1, __ATOMIC_RELAXED,
                                   __HIP_MEMORY_SCOPE_WORKGROUP);
            C0 = A0;
            A0 = up;                                     // lane0 overridden next step
            j += 1;
        }
        if (W > 0) {                                     // speculative next chunk
            #pragma unroll
            for (int k = 0; k < 4; ++k) {
                float4 c = *(const float4*)&bsrc[t + 16 + 4 * k];
                ch[4 * k] = c.x; ch[4 * k + 1] = c.y;
                ch[4 * k + 2] = c.z; ch[4 * k + 3] = c.w;
            }
        }
    }
    if (G == gstar) res[b] = out * GLN2 / (float)(la + lb);
}

// ---------------------------------------------------------------------------
// K3: finalize — losses + 9 MMDs, wave-shuffle reductions.
// ---------------------------------------------------------------------------
__global__ __launch_bounds__(512) void finalize_kernel(const float* __restrict__ res,
                                                       const float* __restrict__ G,
                                                       float* __restrict__ out) {
    __shared__ float wpart[9][8];
    __shared__ float bws[9];
    __shared__ float mmds[9];
    __shared__ float wloss[NW];
    __shared__ int   wnzr[NW];
    int t = threadIdx.x, lane = t & 63, wv = t >> 6;

    if (t < NW) {
        int w = t;
        float dg[NG], dn[NF + NR];
        for (int g = 0; g < NG; ++g) dg[g] = res[w * M_OTH + g];
        for (int q2 = 0; q2 < NF + NR; ++q2) dn[q2] = res[w * M_OTH + NG + q2];
        float sum_s = 0.f, sum_r = 0.f;
        int nzs = 0, nzr = 0;
        for (int g = 0; g < NG; ++g) {
            for (int f = 0; f < NF; ++f) {
                float v = dg[g] + 1.0f - dn[f];
                if (v > 0.f) { sum_s += v; nzs++; }
            }
            for (int r = 0; r < NR; ++r) {
                float v = dg[g] + 1.5f - dn[NF + r];
                if (v > 0.f) { sum_r += v; nzr++; }
            }
        }
        float ca = (dg[0] + dg[1] + dg[2] + dg[3] + dg[4]) / 5.0f;
        float cb = (dn[0] + dn[1] + dn[2] + dn[3]) * 0.25f;
        float intra = 0.f;
        for (int g = 0; g < NG; ++g) intra += dg[g] - ca;
        float inter = fmaxf(0.f, 1.0f - fabsf(ca - cb));
        float lv = (sum_s + sum_r) / (float)(nzs + nzr + 1);
        float bce = 0.f;
        for (int r = 0; r < NR; ++r) {
            float x = dn[NF + r] - dg[0];
            float ls = (x >= 0.f) ? -log1pf(expf(-x)) : (x - log1pf(expf(x)));
            bce += ls;
        }
        bce = -bce / 5.0f;
        wloss[w] = bce + lv + intra * 0.01f + inter * 0.01f;
        wnzr[w] = nzr;
    }

    const int pi[9] = {0, 0, 0, 1, 1, 2, 2, 3, 3};
    const int pj[9] = {1, 2, 3, 2, 3, 1, 3, 1, 2};
    int pp = t / 22, qq = t % 22;
    bool act = t < 484;
    float l2v[9];
    #pragma unroll
    for (int p = 0; p < 9; ++p) {
        float v = 0.f;
        if (act) {
            int wi = pi[p], wj = pj[p];
            int gp = (pp < 11) ? wi * SEGN + pp : wj * SEGN + (pp - 11);
            int gq = (qq < 11) ? wi * SEGN + qq : wj * SEGN + (qq - 11);
            v = fmaxf(G[gp * NSEG + gp] + G[gq * NSEG + gq] - 2.f * G[gp * NSEG + gq], 0.f);
        }
        l2v[p] = v;
    }
    #pragma unroll
    for (int p = 0; p < 9; ++p) {
        float r = l2v[p];
        #pragma unroll
        for (int s = 32; s > 0; s >>= 1) r += __shfl_xor(r, s);
        if (lane == 0) wpart[p][wv] = r;
    }
    __syncthreads();
    if (t < 9) {
        float s = 0.f;
        #pragma unroll
        for (int k = 0; k < 8; ++k) s += wpart[t][k];
        bws[t] = s * (1.0f / 462.0f) * 0.25f;
    }
    __syncthreads();
    float sgn = ((pp < 11) == (qq < 11)) ? 1.f : -1.f;
    #pragma unroll
    for (int p = 0; p < 9; ++p) {
        float kv = 0.f;
        if (act) {
            float x = -l2v[p] / bws[p];
            kv = sgn * (__expf(x) + __expf(x * 0.5f) + __expf(x * 0.25f) +
                        __expf(x * 0.125f) + __expf(x * 0.0625f));
        }
        #pragma unroll
        for (int s = 32; s > 0; s >>= 1) kv += __shfl_xor(kv, s);
        if (lane == 0) wpart[p][wv] = kv;
    }
    __syncthreads();
    if (t < 9) {
        float s = 0.f;
        #pragma unroll
        for (int k = 0; k < 8; ++k) s += wpart[t][k];
        mmds[t] = s / 121.0f;
    }
    __syncthreads();
    if (t == 0) {
        float loss = 0.25f * (wloss[0] + wloss[1] + wloss[2] + wloss[3]);
        float mx = 0.f;
        for (int p = 0; p < 9; ++p) mx = fmaxf(mx, mmds[p]);
        out[0] = loss + 0.1f * mx;
        out[1] = (float)(wnzr[0] + wnzr[1] + wnzr[2] + wnzr[3]);
    }
}

// ---------------------------------------------------------------------------
extern "C" void kernel_launch(void* const* d_in, const int* in_sizes, int n_in,
                              void* d_out, int out_size, void* d_ws, size_t ws_size,
                              hipStream_t stream) {
    const float* data = (const float*)d_in[0];
    const int* lens = (const int*)d_in[1];

    float* DS  = (float*)d_ws;                               // 60*512*512 floats
    float* res = DS + (size_t)NB * 512 * 512;                // 60 floats
    float* G   = res + 64;                                   // 44*44 floats
    float* out = (float*)d_out;

    dim3 g1(4, 4, NB), b1(16, 16);
    sqdist_kernel<<<g1, b1, 0, stream>>>(data, lens, DS);
    dtw_gram_kernel<<<GRAM_BLK0 + 66, 256, 0, stream>>>(DS, lens, data, res, G);
    finalize_kernel<<<1, 512, 0, stream>>>(res, G, out);
}